// Round 1
// baseline (79.815 us; speedup 1.0000x reference)
//
#include <hip/hip_runtime.h>
#include <math.h>

#define H    64
#define N    256
#define D    128
#define L    16
#define ROW  (D + H + N)          // 448
#define F3IN (N * ROW)            // 114688

__device__ __forceinline__ float sigmoidf_(float x) {
    return 1.0f / (1.0f + expf(-x));
}

// ---------------------------------------------------------------------------
// Kernel 1: embedding gather + GRU (sequential over L=16) + Wa^T g / Wb^T g.
// Single block of 192 threads (= 3H). Each thread owns one row of W_ih/W_hh,
// register-cached. h lives in LDS.
// ---------------------------------------------------------------------------
__global__ __launch_bounds__(192) void k_encoder(
    const int* __restrict__ token_ids, const float* __restrict__ emb_table,
    const float* __restrict__ Wih, const float* __restrict__ Whh,
    const float* __restrict__ bih, const float* __restrict__ bhh,
    const float* __restrict__ f1W,
    float* __restrict__ g_out, float* __restrict__ wag_out,
    float* __restrict__ wbg_out)
{
    __shared__ float emb[L][H];
    __shared__ float h[H];
    __shared__ float hnew[H];
    __shared__ float gi_s[3 * H];
    __shared__ float gh_s[3 * H];

    const int k = threadIdx.x;  // 0..191

    for (int idx = k; idx < L * H; idx += 192) {
        int t = idx >> 6, d = idx & 63;
        emb[t][d] = emb_table[token_ids[t] * H + d];
    }
    if (k < H) h[k] = 0.0f;

    // register-cache my gate row
    float wih[H], whh[H];
#pragma unroll
    for (int d = 0; d < H; ++d) {
        wih[d] = Wih[k * H + d];
        whh[d] = Whh[k * H + d];
    }
    const float bi = bih[k], bh = bhh[k];
    __syncthreads();

    for (int t = 0; t < L; ++t) {
        float gi = bi, gh = bh;
#pragma unroll
        for (int d = 0; d < H; ++d) {
            gi += wih[d] * emb[t][d];
            gh += whh[d] * h[d];
        }
        gi_s[k] = gi;
        gh_s[k] = gh;
        __syncthreads();
        if (k < H) {
            float r = sigmoidf_(gi_s[k] + gh_s[k]);
            float z = sigmoidf_(gi_s[H + k] + gh_s[H + k]);
            float n = tanhf(gi_s[2 * H + k] + r * gh_s[2 * H + k]);
            hnew[k] = (1.0f - z) * n + z * h[k];
        }
        __syncthreads();
        if (k < H) h[k] = hnew[k];
        __syncthreads();
    }

    // wa_g[c] = sum_k f1W[k,     c] * g[k]   (c in [0,128))
    // wb_g[c] = sum_k f1W[k, 128+c] * g[k]
    for (int m = k; m < 2 * D; m += 192) {
        float s = 0.0f;
#pragma unroll
        for (int kk = 0; kk < H; ++kk) s += f1W[kk * (2 * D) + m] * h[kk];
        if (m < D) wag_out[m] = s;
        else       wbg_out[m - D] = s;
    }
    if (k < H) g_out[k] = h[k];
}

// ---------------------------------------------------------------------------
// Kernel 2: u = obs@wag, v = obs@wbg, factorized global softmax.
// softmax(flat Z), Z_ij = u_i + v_j + c  =>  p_ij = eu_i*ev_j/(Su*Sv).
// Single block of 256 threads, thread i owns row i of obs.
// ---------------------------------------------------------------------------
__global__ __launch_bounds__(256) void k_softmax(
    const float* __restrict__ obs, const float* __restrict__ wag,
    const float* __restrict__ wbg,
    float* __restrict__ eu_out, float* __restrict__ ev_out,
    float* __restrict__ scale_out)
{
    __shared__ float wa_s[D];
    __shared__ float wb_s[D];
    __shared__ float red[256];

    const int i = threadIdx.x;
    if (i < D) wa_s[i] = wag[i];
    else       wb_s[i - D] = wbg[i - D];
    __syncthreads();

    const float4* rowp = (const float4*)(obs + i * D);
    float u = 0.0f, v = 0.0f;
#pragma unroll
    for (int c = 0; c < D / 4; ++c) {
        float4 o = rowp[c];
        u += o.x * wa_s[4 * c] + o.y * wa_s[4 * c + 1] + o.z * wa_s[4 * c + 2] + o.w * wa_s[4 * c + 3];
        v += o.x * wb_s[4 * c] + o.y * wb_s[4 * c + 1] + o.z * wb_s[4 * c + 2] + o.w * wb_s[4 * c + 3];
    }

    // max(u)
    red[i] = u; __syncthreads();
    for (int s = 128; s > 0; s >>= 1) { if (i < s) red[i] = fmaxf(red[i], red[i + s]); __syncthreads(); }
    const float mu = red[0]; __syncthreads();
    const float eui = expf(u - mu);
    red[i] = eui; __syncthreads();
    for (int s = 128; s > 0; s >>= 1) { if (i < s) red[i] += red[i + s]; __syncthreads(); }
    const float Su = red[0]; __syncthreads();

    // max(v)
    red[i] = v; __syncthreads();
    for (int s = 128; s > 0; s >>= 1) { if (i < s) red[i] = fmaxf(red[i], red[i + s]); __syncthreads(); }
    const float mv = red[0]; __syncthreads();
    const float evi = expf(v - mv);
    red[i] = evi; __syncthreads();
    for (int s = 128; s > 0; s >>= 1) { if (i < s) red[i] += red[i + s]; __syncthreads(); }
    const float Sv = red[0];

    eu_out[i] = eui;
    ev_out[i] = evi;
    if (i == 0) scale_out[0] = 1.0f / (Su * Sv);
}

// ---------------------------------------------------------------------------
// Kernel 3: materialize x = concat_i [ obs_i | g | p_i ]   (114688 floats)
// ---------------------------------------------------------------------------
__global__ __launch_bounds__(256) void k_buildx(
    const float* __restrict__ obs, const float* __restrict__ g,
    const float* __restrict__ eu, const float* __restrict__ ev,
    const float* __restrict__ scale, float* __restrict__ x)
{
    int idx = blockIdx.x * 256 + threadIdx.x;
    if (idx >= F3IN) return;
    int i = idx / ROW;
    int c = idx - i * ROW;
    float val;
    if (c < D)          val = obs[i * D + c];
    else if (c < D + H) val = g[c - D];
    else                val = eu[i] * ev[c - D - H] * scale[0];
    x[idx] = val;
}

// ---------------------------------------------------------------------------
// Kernel 4: h1 = relu(W1 @ x + b1)   -- 512 x 114688, the 224 MiB streamer.
// One block per row, 256 threads, float4 loads, deterministic tree reduce.
// ---------------------------------------------------------------------------
__global__ __launch_bounds__(256) void k_matvec1(
    const float* __restrict__ W1, const float* __restrict__ b1,
    const float* __restrict__ x, float* __restrict__ h1)
{
    const int row = blockIdx.x;
    const float4* w  = (const float4*)(W1 + (size_t)row * F3IN);
    const float4* xv = (const float4*)x;

    float sum = 0.0f;
    for (int c = threadIdx.x; c < F3IN / 4; c += 256) {
        float4 a = w[c];
        float4 b = xv[c];
        sum += a.x * b.x + a.y * b.y + a.z * b.z + a.w * b.w;
    }

    __shared__ float red[256];
    red[threadIdx.x] = sum; __syncthreads();
    for (int s = 128; s > 0; s >>= 1) {
        if (threadIdx.x < s) red[threadIdx.x] += red[threadIdx.x + s];
        __syncthreads();
    }
    if (threadIdx.x == 0) h1[row] = fmaxf(red[0] + b1[row], 0.0f);
}

// ---------------------------------------------------------------------------
// Kernel 5: out = W2 @ h1 + b2   -- 40 x 512
// ---------------------------------------------------------------------------
__global__ __launch_bounds__(64) void k_out(
    const float* __restrict__ W2, const float* __restrict__ b2,
    const float* __restrict__ h1, float* __restrict__ out)
{
    const int row = blockIdx.x;   // 0..39
    const int lane = threadIdx.x; // 0..63
    float sum = 0.0f;
    for (int c = lane; c < 512; c += 64) sum += W2[row * 512 + c] * h1[c];
#pragma unroll
    for (int off = 32; off > 0; off >>= 1) sum += __shfl_down(sum, off, 64);
    if (lane == 0) out[row] = sum + b2[row];
}

// ---------------------------------------------------------------------------
extern "C" void kernel_launch(void* const* d_in, const int* in_sizes, int n_in,
                              void* d_out, int out_size, void* d_ws, size_t ws_size,
                              hipStream_t stream)
{
    const float* obs       = (const float*)d_in[0];
    const int*   token_ids = (const int*)  d_in[1];
    const float* emb_table = (const float*)d_in[2];
    const float* Wih       = (const float*)d_in[3];
    const float* Whh       = (const float*)d_in[4];
    const float* bih       = (const float*)d_in[5];
    const float* bhh       = (const float*)d_in[6];
    const float* f1W       = (const float*)d_in[7];
    // d_in[8] = f1_b : cancels inside the flat softmax (Z_ij = u_i+v_j+const)
    const float* W1        = (const float*)d_in[9];
    const float* b1        = (const float*)d_in[10];
    const float* W2        = (const float*)d_in[11];
    const float* b2        = (const float*)d_in[12];

    float* ws    = (float*)d_ws;
    float* g     = ws;            // 64
    float* wag   = ws + 64;       // 128
    float* wbg   = ws + 192;      // 128
    float* eu    = ws + 320;      // 256
    float* ev    = ws + 576;      // 256
    float* scale = ws + 832;      // 1 (+7 pad, keeps x 16B-aligned)
    float* x     = ws + 840;      // 114688
    float* h1    = ws + 840 + F3IN; // 512
    float* out   = (float*)d_out;

    k_encoder<<<1, 192, 0, stream>>>(token_ids, emb_table, Wih, Whh, bih, bhh,
                                     f1W, g, wag, wbg);
    k_softmax<<<1, 256, 0, stream>>>(obs, wag, wbg, eu, ev, scale);
    k_buildx<<<(F3IN + 255) / 256, 256, 0, stream>>>(obs, g, eu, ev, scale, x);
    k_matvec1<<<512, 256, 0, stream>>>(W1, b1, x, h1);
    k_out<<<40, 64, 0, stream>>>(W2, b2, h1, out);
}

// Round 2
// 76.662 us; speedup vs baseline: 1.0411x; 1.0411x over previous
//
#include <hip/hip_runtime.h>
#include <math.h>

#define H    64
#define N    256
#define D    128
#define L    16
#define ROW  (D + H + N)          // 448
#define F3IN (N * ROW)            // 114688
#define F3IN4 (F3IN / 4)          // 28672 float4 per W1 row
#define CHUNK4 (F3IN4 / 4)        // 7168 float4 per chunk

__device__ __forceinline__ float sigmoidf_(float x) {
    return 1.0f / (1.0f + expf(-x));
}

// ---------------------------------------------------------------------------
// Kernel 1: embedding gather + GRU (L=16) + Wa^T g / Wb^T g + factorized
// global softmax. One block, 256 threads (GRU gate rows use threads 0..191).
// softmax(flat Z), Z_ij = u_i + v_j + c  =>  p_ij = eu_i*ev_j/(Su*Sv); the
// constant (f1_b . g) cancels exactly.
// ---------------------------------------------------------------------------
__global__ __launch_bounds__(256) void k_enc_softmax(
    const int* __restrict__ token_ids, const float* __restrict__ emb_table,
    const float* __restrict__ Wih, const float* __restrict__ Whh,
    const float* __restrict__ bih, const float* __restrict__ bhh,
    const float* __restrict__ f1W, const float* __restrict__ obs,
    float* __restrict__ g_out, float* __restrict__ eu_out,
    float* __restrict__ ev_out, float* __restrict__ scale_out)
{
    __shared__ float emb[L][H];
    __shared__ float h[H];
    __shared__ float hnew[H];
    __shared__ float gi_s[3 * H];
    __shared__ float gh_s[3 * H];
    __shared__ float wa_s[D];
    __shared__ float wb_s[D];
    __shared__ float red[256];

    const int k = threadIdx.x;  // 0..255

    for (int idx = k; idx < L * H; idx += 256) {
        int t = idx >> 6, d = idx & 63;
        emb[t][d] = emb_table[token_ids[t] * H + d];
    }
    if (k < H) h[k] = 0.0f;

    // threads 0..191: register-cache gate row as float4[16]
    float4 wih4[16], whh4[16];
    float bi = 0.0f, bh = 0.0f;
    if (k < 3 * H) {
        const float4* wi = (const float4*)(Wih + k * H);
        const float4* wh = (const float4*)(Whh + k * H);
#pragma unroll
        for (int c = 0; c < 16; ++c) { wih4[c] = wi[c]; whh4[c] = wh[c]; }
        bi = bih[k]; bh = bhh[k];
    }
    __syncthreads();

    for (int t = 0; t < L; ++t) {
        if (k < 3 * H) {
            const float4* et = (const float4*)emb[t];
            const float4* hv = (const float4*)h;
            float gi = bi, gh = bh;
#pragma unroll
            for (int c = 0; c < 16; ++c) {
                float4 e = et[c], hh = hv[c];
                gi += wih4[c].x * e.x + wih4[c].y * e.y + wih4[c].z * e.z + wih4[c].w * e.w;
                gh += whh4[c].x * hh.x + whh4[c].y * hh.y + whh4[c].z * hh.z + whh4[c].w * hh.w;
            }
            gi_s[k] = gi;
            gh_s[k] = gh;
        }
        __syncthreads();
        if (k < H) {
            float r = sigmoidf_(gi_s[k] + gh_s[k]);
            float z = sigmoidf_(gi_s[H + k] + gh_s[H + k]);
            float n = tanhf(gi_s[2 * H + k] + r * gh_s[2 * H + k]);
            hnew[k] = (1.0f - z) * n + z * h[k];
        }
        __syncthreads();
        if (k < H) h[k] = hnew[k];
        __syncthreads();
    }

    // wa_s[m] = sum_kk f1W[kk, m] * h[kk]; wb_s for columns 128..255.
    // (coalesced: for fixed kk, 256 threads read consecutive floats)
    {
        float s = 0.0f;
#pragma unroll 8
        for (int kk = 0; kk < H; ++kk) s += f1W[kk * (2 * D) + k] * h[kk];
        if (k < D) wa_s[k] = s;
        else       wb_s[k - D] = s;
        if (k < H) g_out[k] = h[k];
    }
    __syncthreads();

    // u_i = obs_i . wa, v_i = obs_i . wb  (thread i owns row i)
    const float4* rowp = (const float4*)(obs + k * D);
    const float4* wav = (const float4*)wa_s;
    const float4* wbv = (const float4*)wb_s;
    float u = 0.0f, v = 0.0f;
#pragma unroll
    for (int c = 0; c < D / 4; ++c) {
        float4 o = rowp[c], a = wav[c], b = wbv[c];
        u += o.x * a.x + o.y * a.y + o.z * a.z + o.w * a.w;
        v += o.x * b.x + o.y * b.y + o.z * b.z + o.w * b.w;
    }

    red[k] = u; __syncthreads();
    for (int s = 128; s > 0; s >>= 1) { if (k < s) red[k] = fmaxf(red[k], red[k + s]); __syncthreads(); }
    const float mu = red[0]; __syncthreads();
    const float eui = expf(u - mu);
    red[k] = eui; __syncthreads();
    for (int s = 128; s > 0; s >>= 1) { if (k < s) red[k] += red[k + s]; __syncthreads(); }
    const float Su = red[0]; __syncthreads();

    red[k] = v; __syncthreads();
    for (int s = 128; s > 0; s >>= 1) { if (k < s) red[k] = fmaxf(red[k], red[k + s]); __syncthreads(); }
    const float mv = red[0]; __syncthreads();
    const float evi = expf(v - mv);
    red[k] = evi; __syncthreads();
    for (int s = 128; s > 0; s >>= 1) { if (k < s) red[k] += red[k + s]; __syncthreads(); }
    const float Sv = red[0];

    eu_out[k] = eui;
    ev_out[k] = evi;
    if (k == 0) scale_out[0] = 1.0f / (Su * Sv);
}

// ---------------------------------------------------------------------------
// Kernel 2: x = concat_i [ obs_i | g | p_i ], float4 per thread, no division.
// block = row i (256 blocks), threads 0..111 each write one float4.
// ---------------------------------------------------------------------------
__global__ __launch_bounds__(128) void k_buildx(
    const float* __restrict__ obs, const float* __restrict__ g,
    const float* __restrict__ eu, const float* __restrict__ ev,
    const float* __restrict__ scale, float* __restrict__ x)
{
    const int i = blockIdx.x;
    const int t = threadIdx.x;
    if (t >= ROW / 4) return;   // 112 float4 per row

    float4 val;
    if (t < D / 4) {                       // obs_i
        val = ((const float4*)(obs + i * D))[t];
    } else if (t < (D + H) / 4) {          // g
        val = ((const float4*)g)[t - D / 4];
    } else {                               // p_i = eu_i * scale * ev
        float4 e = ((const float4*)ev)[t - (D + H) / 4];
        float s = eu[i] * scale[0];
        val = make_float4(e.x * s, e.y * s, e.z * s, e.w * s);
    }
    ((float4*)x)[i * (ROW / 4) + t] = val;
}

// ---------------------------------------------------------------------------
// Kernel 3: partial[row*4+chunk] = dot(W1[row, chunk], x[chunk]).
// 2048 blocks x 256 threads = 32 waves/CU. Two accumulators for MLP.
// ---------------------------------------------------------------------------
__global__ __launch_bounds__(256) void k_matvec1(
    const float* __restrict__ W1, const float* __restrict__ x,
    float* __restrict__ partial)
{
    const int bid   = blockIdx.x;
    const int row   = bid >> 2;
    const int chunk = bid & 3;

    const float4* w  = (const float4*)W1 + (size_t)row * F3IN4 + chunk * CHUNK4;
    const float4* xv = (const float4*)x + chunk * CHUNK4;

    float s0 = 0.0f, s1 = 0.0f;
    for (int c = threadIdx.x; c < CHUNK4; c += 512) {
        float4 a0 = w[c],       b0 = xv[c];
        float4 a1 = w[c + 256], b1 = xv[c + 256];
        s0 += a0.x * b0.x + a0.y * b0.y + a0.z * b0.z + a0.w * b0.w;
        s1 += a1.x * b1.x + a1.y * b1.y + a1.z * b1.z + a1.w * b1.w;
    }
    float sum = s0 + s1;

    __shared__ float red[256];
    red[threadIdx.x] = sum; __syncthreads();
    for (int s = 128; s > 0; s >>= 1) {
        if (threadIdx.x < s) red[threadIdx.x] += red[threadIdx.x + s];
        __syncthreads();
    }
    if (threadIdx.x == 0) partial[bid] = red[0];
}

// ---------------------------------------------------------------------------
// Kernel 4: h1 = relu(sum partials + b1); out = W2 @ h1 + b2. One block.
// ---------------------------------------------------------------------------
__global__ __launch_bounds__(512) void k_finish(
    const float* __restrict__ partial, const float* __restrict__ b1,
    const float* __restrict__ W2, const float* __restrict__ b2,
    float* __restrict__ out)
{
    __shared__ float h1s[512];
    const int r = threadIdx.x;
    {
        const float4 p = ((const float4*)partial)[r];
        h1s[r] = fmaxf(p.x + p.y + p.z + p.w + b1[r], 0.0f);
    }
    __syncthreads();

    const int wave = r >> 6, lane = r & 63;
    for (int row = wave; row < 40; row += 8) {
        float s = 0.0f;
#pragma unroll
        for (int c = 0; c < 8; ++c) s += W2[row * 512 + lane + c * 64] * h1s[lane + c * 64];
#pragma unroll
        for (int off = 32; off > 0; off >>= 1) s += __shfl_down(s, off, 64);
        if (lane == 0) out[row] = s + b2[row];
    }
}

// ---------------------------------------------------------------------------
extern "C" void kernel_launch(void* const* d_in, const int* in_sizes, int n_in,
                              void* d_out, int out_size, void* d_ws, size_t ws_size,
                              hipStream_t stream)
{
    const float* obs       = (const float*)d_in[0];
    const int*   token_ids = (const int*)  d_in[1];
    const float* emb_table = (const float*)d_in[2];
    const float* Wih       = (const float*)d_in[3];
    const float* Whh       = (const float*)d_in[4];
    const float* bih       = (const float*)d_in[5];
    const float* bhh       = (const float*)d_in[6];
    const float* f1W       = (const float*)d_in[7];
    // d_in[8] = f1_b : cancels inside the flat softmax
    const float* W1        = (const float*)d_in[9];
    const float* b1        = (const float*)d_in[10];
    const float* W2        = (const float*)d_in[11];
    const float* b2        = (const float*)d_in[12];

    float* ws    = (float*)d_ws;
    float* g     = ws;              // 64
    float* eu    = ws + 64;         // 256
    float* ev    = ws + 320;        // 256
    float* scale = ws + 576;        // 1 (+63 pad -> x 16B aligned)
    float* x     = ws + 640;        // 114688
    float* part  = ws + 640 + F3IN; // 2048
    float* out   = (float*)d_out;

    k_enc_softmax<<<1, 256, 0, stream>>>(token_ids, emb_table, Wih, Whh, bih,
                                         bhh, f1W, obs, g, eu, ev, scale);
    k_buildx<<<N, 128, 0, stream>>>(obs, g, eu, ev, scale, x);
    k_matvec1<<<2048, 256, 0, stream>>>(W1, x, part);
    k_finish<<<1, 512, 0, stream>>>(part, b1, W2, b2, out);
}